// Round 1
// baseline (344.778 us; speedup 1.0000x reference)
//
#include <hip/hip_runtime.h>
#include <math.h>

#define B_DIM 64
#define C_DIM 768
#define S_DIM 1024   // 32*32 spatial
#define E_DIM 64
#define GROUPS 12    // channel groups per batch
#define CG     64    // channels per group; GROUPS*CG == C_DIM

// Workspace layout:
//   [0, B*C*4)            pooled[B][C]  (float)
//   [B*C*4, B*C*4+B*4)    per-batch arrival counters (int), zeroed by a
//                         256 B hipMemsetAsync node that replays with the graph.
#define POOL_BYTES (B_DIM * C_DIM * sizeof(float))

// ---------------------------------------------------------------------------
// Fused kernel. Grid = B*GROUPS = 768 blocks, 256 threads (4 waves).
// Phase 1: each wave pools 16 channel rows (identical arithmetic to the old
//          pool_kernel: 4x float4 per lane, same add tree, same butterfly).
// Phase 2: per-batch last-arrival block (deadlock-free, no spinning) runs the
//          gate: identical arithmetic to the old gate_kernel.
// Cross-block visibility via agent-scope atomics (safe across XCD L2s).
// ---------------------------------------------------------------------------
__global__ __launch_bounds__(256) void fused_gate(const float* __restrict__ x,
                                                  const float* __restrict__ Wm,
                                                  const float* __restrict__ bvec,
                                                  const float* __restrict__ route_bias,
                                                  int K,
                                                  float* __restrict__ ws_pool,
                                                  int*   __restrict__ ws_cnt,
                                                  float* __restrict__ out) {
    __shared__ __align__(16) float s_pool[C_DIM];
    __shared__ float s_scores[E_DIM];
    __shared__ int   s_last;

    const int tid  = threadIdx.x;
    const int wv   = tid >> 6;          // wave 0..3
    const int lane = tid & 63;
    const int b    = blockIdx.x & (B_DIM - 1);   // batch (fast dim)
    const int g    = blockIdx.x >> 6;            // channel group 0..11

    // ---- phase 1: pool CG channels, 16 per wave ----
    const int c0 = g * CG + wv * 16;    // first channel for this wave
    const float4* xbase = (const float4*)(x + ((size_t)b * C_DIM + c0) * S_DIM);

#pragma unroll 2
    for (int i = 0; i < 16; ++i) {
        const float4* p = xbase + (size_t)i * (S_DIM / 4);
        float s = 0.0f;
#pragma unroll
        for (int k = 0; k < 4; ++k) {
            float4 v = p[k * 64 + lane];
            s += (v.x + v.y) + (v.z + v.w);
        }
#pragma unroll
        for (int off = 1; off < 64; off <<= 1) s += __shfl_xor(s, off);
        if (lane == 0) {
            __hip_atomic_store(&ws_pool[(size_t)b * C_DIM + c0 + i],
                               s * (1.0f / (float)S_DIM),
                               __ATOMIC_RELAXED, __HIP_MEMORY_SCOPE_AGENT);
        }
    }

    __syncthreads();
    if (tid == 0) {
        __threadfence();   // belt-and-braces release of the pooled stores
        int old = __hip_atomic_fetch_add(&ws_cnt[b], 1, __ATOMIC_ACQ_REL,
                                         __HIP_MEMORY_SCOPE_AGENT);
        s_last = (old == GROUPS - 1) ? 1 : 0;
    }
    __syncthreads();
    if (!s_last) return;   // not the last arrival for this batch

    // ---- phase 2: gate for batch b (identical math to old gate_kernel) ----
    __threadfence();       // acquire side
    const float* prow = ws_pool + (size_t)b * C_DIM;
    for (int i = tid; i < C_DIM; i += 256)
        s_pool[i] = __hip_atomic_load(&prow[i], __ATOMIC_RELAXED,
                                      __HIP_MEMORY_SCOPE_AGENT);
    __syncthreads();

    // dot product: expert e handled by 4 consecutive threads (q = chunk)
    const int e = tid >> 2;      // 0..63
    const int q = tid & 3;       // 0..3, each covers 192 channels
    const float4* wrow  = (const float4*)(Wm + (size_t)e * C_DIM + q * 192);
    const float4* prow4 = (const float4*)(s_pool + q * 192);
    float acc = 0.0f;
#pragma unroll 8
    for (int i = 0; i < 48; ++i) {
        float4 wvv = wrow[i];
        float4 pv  = prow4[i];
        acc += wvv.x * pv.x + wvv.y * pv.y + wvv.z * pv.z + wvv.w * pv.w;
    }
    acc += __shfl_xor(acc, 1);
    acc += __shfl_xor(acc, 2);
    if (q == 0) {
        float z = acc + bvec[e];
        s_scores[e] = 1.0f / (1.0f + expf(-z));
    }
    __syncthreads();

    // top-K selection + normalization by wave 0
    if (tid < 64) {
        const int l = tid;
        float myval = s_scores[l] + route_bias[l];  // biased (selection)
        int  sel_idx  = 0;
        bool have_sel = false;

        for (int k = 0; k < K; ++k) {
            float v = myval;
            int   i = l;
#pragma unroll
            for (int off = 1; off < 64; off <<= 1) {
                float ov = __shfl_xor(v, off);
                int   oi = __shfl_xor(i, off);
                // argmax with tie-break to smaller index (lax.top_k semantics)
                if (ov > v || (ov == v && oi < i)) { v = ov; i = oi; }
            }
            if (l == k) { sel_idx = i; have_sel = true; }
            if (l == i) myval = -INFINITY;   // remove winner
        }

        float w = have_sel ? s_scores[sel_idx] : 0.0f;  // original score
        float tot = w;
#pragma unroll
        for (int off = 1; off < 64; off <<= 1) tot += __shfl_xor(tot, off);

        if (l < K) {
            // weights [B,K] then indices [B,K] (as float), flat in d_out
            out[(size_t)b * K + l] = w / tot;  // ROUTE_SCALE == 1.0
            out[(size_t)B_DIM * K + (size_t)b * K + l] = (float)sel_idx;
        }
    }
}

extern "C" void kernel_launch(void* const* d_in, const int* in_sizes, int n_in,
                              void* d_out, int out_size, void* d_ws, size_t ws_size,
                              hipStream_t stream) {
    const float* x          = (const float*)d_in[0];
    const float* Wm         = (const float*)d_in[1];
    const float* bvec       = (const float*)d_in[2];
    const float* route_bias = (const float*)d_in[3];
    // d_in[4] is topk (device scalar); K also derivable from out_size:
    const int K = out_size / (2 * B_DIM);   // = 8

    float* ws_pool = (float*)d_ws;
    int*   ws_cnt  = (int*)((char*)d_ws + POOL_BYTES);
    float* out     = (float*)d_out;

    // zero the 64 per-batch counters; this node replays with the graph, so
    // workspace re-poisoning between iterations is harmless.
    hipMemsetAsync(ws_cnt, 0, B_DIM * sizeof(int), stream);

    fused_gate<<<B_DIM * GROUPS, 256, 0, stream>>>(x, Wm, bvec, route_bias, K,
                                                   ws_pool, ws_cnt, out);
}

// Round 2
// 284.785 us; speedup vs baseline: 1.2107x; 1.2107x over previous
//
#include <hip/hip_runtime.h>
#include <math.h>

#define B_DIM 64
#define C_DIM 768
#define S_DIM 1024   // 32*32 spatial
#define E_DIM 64

// ---------------------------------------------------------------------------
// Kernel 1: global average pool. One 64-lane wave per (b,c) row of 1024 floats.
// Each lane loads 4 float4 (coalesced, 16B/lane), wave shfl reduction.
// 49152 independent waves, 8 blocks/CU resident -> pure BW-bound, ~32-40 us.
// (Round-1 lesson: do NOT trade this TLP for fusion; serial multi-row waves +
// agent-scope coherence ops were latency-bound at 154 us.)
// ---------------------------------------------------------------------------
__global__ __launch_bounds__(256) void pool_kernel(const float* __restrict__ x,
                                                   float* __restrict__ pooled,
                                                   int nrows) {
    int wave = (int)((blockIdx.x * blockDim.x + threadIdx.x) >> 6);
    int lane = threadIdx.x & 63;
    if (wave >= nrows) return;

    const float4* p = (const float4*)(x + (size_t)wave * S_DIM);
    float s = 0.0f;
#pragma unroll
    for (int k = 0; k < 4; ++k) {
        float4 v = p[k * 64 + lane];
        s += (v.x + v.y) + (v.z + v.w);
    }
#pragma unroll
    for (int off = 1; off < 64; off <<= 1) s += __shfl_xor(s, off);
    if (lane == 0) pooled[wave] = s * (1.0f / (float)S_DIM);
}

// ---------------------------------------------------------------------------
// Kernel 2: per batch row: scores = sigmoid(pooled @ W^T + b); top-K on
// scores + route_bias; gather original scores; normalize; write out.
// Block = 256 threads, grid = B. 4 threads per expert for the 768-dot.
// FP order kept EXACTLY as the verified round-0 version (absmax == 0.0;
// index outputs are exact-compare, so no reassociation allowed).
// ---------------------------------------------------------------------------
__global__ __launch_bounds__(256) void gate_kernel(const float* __restrict__ pooled,
                                                   const float* __restrict__ Wm,
                                                   const float* __restrict__ bvec,
                                                   const float* __restrict__ route_bias,
                                                   int K,
                                                   float* __restrict__ out) {
    __shared__ __align__(16) float s_pool[C_DIM];
    __shared__ float s_scores[E_DIM];

    const int b   = blockIdx.x;
    const int tid = threadIdx.x;

    // stage pooled[b,:] into LDS (coalesced)
    const float* prow = pooled + (size_t)b * C_DIM;
    for (int i = tid; i < C_DIM; i += 256) s_pool[i] = prow[i];
    __syncthreads();

    // dot product: expert e handled by 4 consecutive threads (q = chunk)
    const int e = tid >> 2;      // 0..63
    const int q = tid & 3;       // 0..3, each covers 192 channels
    const float4* wrow  = (const float4*)(Wm + (size_t)e * C_DIM + q * 192);
    const float4* prow4 = (const float4*)(s_pool + q * 192);
    float acc = 0.0f;
#pragma unroll 8
    for (int i = 0; i < 48; ++i) {
        float4 wv = wrow[i];
        float4 pv = prow4[i];
        acc += wv.x * pv.x + wv.y * pv.y + wv.z * pv.z + wv.w * pv.w;
    }
    // combine the 4 partials (consecutive lanes in the same wave)
    acc += __shfl_xor(acc, 1);
    acc += __shfl_xor(acc, 2);
    if (q == 0) {
        float z = acc + bvec[e];
        s_scores[e] = 1.0f / (1.0f + expf(-z));
    }
    __syncthreads();

    // top-K selection + normalization by wave 0
    if (tid < 64) {
        const int lane = tid;
        float myval = s_scores[lane] + route_bias[lane];  // biased (selection)
        int sel_idx = 0;
        bool have_sel = false;

        for (int k = 0; k < K; ++k) {
            float v = myval;
            int   i = lane;
#pragma unroll
            for (int off = 1; off < 64; off <<= 1) {
                float ov = __shfl_xor(v, off);
                int   oi = __shfl_xor(i, off);
                // argmax with tie-break to smaller index (lax.top_k semantics)
                if (ov > v || (ov == v && oi < i)) { v = ov; i = oi; }
            }
            if (lane == k) { sel_idx = i; have_sel = true; }
            if (lane == i) myval = -INFINITY;   // remove winner
        }

        float w = have_sel ? s_scores[sel_idx] : 0.0f;  // original score
        float tot = w;
#pragma unroll
        for (int off = 1; off < 64; off <<= 1) tot += __shfl_xor(tot, off);

        if (lane < K) {
            // weights [B,K] then indices [B,K] (as float), flat in d_out
            out[(size_t)b * K + lane] = w / tot;  // ROUTE_SCALE == 1.0
            out[(size_t)B_DIM * K + (size_t)b * K + lane] = (float)sel_idx;
        }
    }
}

extern "C" void kernel_launch(void* const* d_in, const int* in_sizes, int n_in,
                              void* d_out, int out_size, void* d_ws, size_t ws_size,
                              hipStream_t stream) {
    const float* x          = (const float*)d_in[0];
    const float* Wm         = (const float*)d_in[1];
    const float* bvec       = (const float*)d_in[2];
    const float* route_bias = (const float*)d_in[3];
    // d_in[4] is topk (device scalar); K also derivable from out_size:
    const int K = out_size / (2 * B_DIM);   // = 8

    float* pooled = (float*)d_ws;           // B*C floats = 196 KB
    float* out    = (float*)d_out;

    const int nrows  = B_DIM * C_DIM;                 // 49152 waves
    const int blocks = (nrows * 64 + 255) / 256;      // 12288
    pool_kernel<<<blocks, 256, 0, stream>>>(x, pooled, nrows);
    gate_kernel<<<B_DIM, 256, 0, stream>>>(pooled, Wm, bvec, route_bias, K, out);
}